// Round 4
// baseline (342.580 us; speedup 1.0000x reference)
//
#include <hip/hip_runtime.h>
#include <hip/hip_bf16.h>

// QuantizedLinear: out[n][o] = scale[o] * dot(x[n,:], (q[o,:]-8)) + bias[o]
// R9 = R6 (verified 128 us / 1074 TF) + one-phase-ahead REGISTER PIPELINING
// of fragment ds_reads: reads for phase p+1 issue inside phase p's MFMA
// region (post-lgkm-drain), so each phase's lgkmcnt(0) drains reads that had
// a full phase in flight (~0 stall) and LDS read service overlaps the MFMA
// clusters instead of serializing with them (R6 wall = reads + MFMA).
// Quadrant order (0,0),(1,0),(1,1),(0,1): each A/B half read once per K-tile
// (24 ds_read_b128, minimal). A = 2 slots, roles swap per tile (compile-time
// via the 2-tile unroll); B = 2 fixed slots (b0,b1). Next-tile A0/B0
// pre-reads issue only after phase 4's vmcnt(4)+barrier (residency proven).
// Barrier/stage/vmcnt skeleton byte-identical to R6. Kept: chunk-XOR LDS
// swizzle (conflicts=0), pre-swizzled global source + linear global_load_lds
// dest, setprio around MFMA, XCD stripe swizzle, fused epilogue, prep.

typedef __attribute__((ext_vector_type(8))) __bf16 bf16x8;
typedef __attribute__((ext_vector_type(4))) float f32x4;

#define GLOBAL_AS __attribute__((address_space(1)))
#define LDS_AS __attribute__((address_space(3)))

#define BM 256
#define BN 256
#define BK 64

__device__ inline unsigned short f32_to_bf16(float f) {
    unsigned int u = __float_as_uint(f);
    unsigned int r = (u + 0x7FFFu + ((u >> 16) & 1u)) >> 16;
    return (unsigned short)r;
}

// ---- merged preprocessing: x fp32 -> bf16 AND packed nibbles -> bf16 ints ----
__global__ void prep(const float* __restrict__ x, unsigned short* __restrict__ xb,
                     const int* __restrict__ wp, unsigned short* __restrict__ wb,
                     int n8x, int n4w) {
    const int stride = gridDim.x * blockDim.x;
    const int total = n8x + n4w;
    for (int i = blockIdx.x * blockDim.x + threadIdx.x; i < total; i += stride) {
        if (i < n8x) {
            float4 a = ((const float4*)x)[2 * i];
            float4 b = ((const float4*)x)[2 * i + 1];
            union { unsigned short h[8]; uint4 u; } o;
            o.h[0] = f32_to_bf16(a.x); o.h[1] = f32_to_bf16(a.y);
            o.h[2] = f32_to_bf16(a.z); o.h[3] = f32_to_bf16(a.w);
            o.h[4] = f32_to_bf16(b.x); o.h[5] = f32_to_bf16(b.y);
            o.h[6] = f32_to_bf16(b.z); o.h[7] = f32_to_bf16(b.w);
            ((uint4*)xb)[i] = o.u;
        } else {
            int k = i - n8x;
            int4 v = ((const int4*)wp)[k];
            int vals[4] = {v.x, v.y, v.z, v.w};
            union { unsigned short h[8]; uint4 u; } o;
#pragma unroll
            for (int t = 0; t < 4; ++t) {
                o.h[2 * t]     = f32_to_bf16((float)((vals[t] & 0xF) - 8));
                o.h[2 * t + 1] = f32_to_bf16((float)(((vals[t] >> 4) & 0xF) - 8));
            }
            ((uint4*)wb)[k] = o.u;
        }
    }
}

// ---- main GEMM: C[m][n] = sum_k A[m][k]*B[n][k]; epilogue scale/bias ----
// 256x256 tile, 8 waves (wm=wave>>2, wn=wave&3). LDS regions per 64KB buffer
// (ushort offsets): A0=0, A1=8192, B0=16384, B1=24576. Buffer stride 32768.
template<int K, int N>
__global__ __launch_bounds__(512, 2) void gemm_bt(
    const unsigned short* __restrict__ A,
    const unsigned short* __restrict__ B,
    const float* __restrict__ scales,
    const float* __restrict__ bias,
    float* __restrict__ C,
    int GY)
{
    constexpr int NT = K / BK;   // 64 K-tiles
    __shared__ __align__(16) unsigned short lds[65536];  // 128 KiB

    const int tid  = threadIdx.x;
    const int wave = tid >> 6;
    const int lane = tid & 63;
    const int wm = wave >> 2;    // 0..1
    const int wn = wave & 3;     // 0..3

    // XCD swizzle: XCD x = bid&7 owns a 2-column stripe of the 16x16 grid.
    const int bid = blockIdx.x;
    const int chunk = gridDim.x >> 3;
    const int sw = (bid & 7) * chunk + (bid >> 3);
    const int bx = sw / GY;
    const int by = sw - bx * GY;
    const int m0 = by * BM;
    const int n0 = bx * BN;

    // fragment LDS byte offsets (relative to a 64KB buffer base)
    const int am = lane & 15;
    const int aq = lane >> 4;
    const int cb = ((aq ^ (am & 7)) << 4);   // swizzled chunk byte, kk=0 (^64 for kk=1)

    int aoff[8], boff[4];
#pragma unroll
    for (int i = 0; i < 8; ++i) {
        int r = (2 * i + wm) * 16 + am;               // tile row 0..255
        aoff[i] = ((i < 4) ? 0 : 16384) + (r & 127) * 128 + cb;
    }
#pragma unroll
    for (int j = 0; j < 4; ++j) {
        int r = (4 * j + wn) * 16 + am;               // tile col 0..255
        boff[j] = 32768 + ((j < 2) ? 0 : 16384) + (r & 127) * 128 + cb;
    }

    // staging: half-tile = 128x64 bf16 = 1024 16B-chunks; thread covers flat
    // chunks tid and 512+tid. LDS dest linear; global source pre-swizzled.
    const int sch = tid & 7;
    const int r0 = tid >> 3;             // 0..63
    const int r1 = (512 + tid) >> 3;     // 64..127
    const size_t g0 = (size_t)r0 * K + (size_t)((sch ^ (r0 & 7)) * 8);
    const size_t g1 = (size_t)r1 * K + (size_t)((sch ^ (r1 & 7)) * 8);
    const int d0 = tid * 8;              // ushort units within region
    const int d1 = (512 + tid) * 8;

    const unsigned short* Abase = A + (size_t)m0 * K;
    const unsigned short* Bbase = B + (size_t)n0 * K;

    f32x4 acc[8][4];
#pragma unroll
    for (int i = 0; i < 8; ++i)
#pragma unroll
        for (int j = 0; j < 4; ++j)
            acc[i][j] = (f32x4){0.f, 0.f, 0.f, 0.f};

    const char* ldsB = (const char*)lds;
    bf16x8 af[2][4][2];   // 2 A slots x 4 row-frags x 2 kk  (64 VGPR)
    bf16x8 bfr[2][2][2];  // b0/b1 slots x 2 col-frags x 2 kk (32 VGPR)

#define STAGE(gbase, half, kcol, uoff)                                            \
    do {                                                                          \
        const unsigned short* _g = (gbase) + (size_t)((half) * 128) * K + (kcol); \
        __builtin_amdgcn_global_load_lds((const GLOBAL_AS void*)(_g + g0),        \
            (LDS_AS void*)(lds + (uoff) + d0), 16, 0, 0);                         \
        __builtin_amdgcn_global_load_lds((const GLOBAL_AS void*)(_g + g1),        \
            (LDS_AS void*)(lds + (uoff) + d1), 16, 0, 0);                         \
    } while (0)

// read A-half mh into slot S from buffer at BYTE offset OBb
#define LDA_S(S, mh, OBb)                                                         \
    _Pragma("unroll") for (int i2 = 0; i2 < 4; ++i2) {                            \
        af[S][i2][0] = *(const bf16x8*)(ldsB + (OBb) + aoff[(mh) * 4 + i2]);      \
        af[S][i2][1] = *(const bf16x8*)(ldsB + (OBb) + (aoff[(mh) * 4 + i2] ^ 64)); \
    }

// read B-half nh into slot S from buffer at BYTE offset OBb
#define LDB_S(S, nh, OBb)                                                         \
    _Pragma("unroll") for (int j2 = 0; j2 < 2; ++j2) {                            \
        bfr[S][j2][0] = *(const bf16x8*)(ldsB + (OBb) + boff[(nh) * 2 + j2]);     \
        bfr[S][j2][1] = *(const bf16x8*)(ldsB + (OBb) + (boff[(nh) * 2 + j2] ^ 64)); \
    }

#define BAR_LG()                                                                  \
    __builtin_amdgcn_s_barrier();                                                 \
    asm volatile("s_waitcnt lgkmcnt(0)" ::: "memory");                            \
    __builtin_amdgcn_sched_barrier(0)

// quadrant (mh,nh) from A slot AS / B slot BS
#define MFMA_Q(AS, BS, mh, nh)                                                    \
    _Pragma("unroll") for (int i2 = 0; i2 < 4; ++i2)                              \
    _Pragma("unroll") for (int j2 = 0; j2 < 2; ++j2) {                            \
        acc[(mh) * 4 + i2][(nh) * 2 + j2] = __builtin_amdgcn_mfma_f32_16x16x32_bf16( \
            af[AS][i2][0], bfr[BS][j2][0], acc[(mh) * 4 + i2][(nh) * 2 + j2], 0, 0, 0); \
        acc[(mh) * 4 + i2][(nh) * 2 + j2] = __builtin_amdgcn_mfma_f32_16x16x32_bf16( \
            af[AS][i2][1], bfr[BS][j2][1], acc[(mh) * 4 + i2][(nh) * 2 + j2], 0, 0, 0); \
    }

// One K-tile = 4 phases, quadrants (0,0),(1,0),(1,1),(0,1).
// A0(t) lives in slot SX (loaded by prev group's p4), A1(t) -> slot SY (p1).
// B0(t) in b-slot0 (prev p4), B1(t) -> b-slot1 (p2).
// Stage schedule identical to R6: p1 B0(t+1)->other, p2 A1(t+1)->other,
// p3 A0(t+2)->cur, p4 B1(t+2)->cur + vmcnt(4). Pre-reads of tile t+1's
// A0/B0 issue in p4 AFTER vmcnt(4)+barrier (residency proven), overlapped
// with p4's MFMA cluster, drained at next group's p1 lgkmcnt(0).
#define GROUP(OB, OUS, OUSo, t, SX, SY)                                           \
    {                                                                             \
        const int kn1 = (((t) + 1 < NT) ? (t) + 1 : NT - 1) * BK;                 \
        const int kn2 = (((t) + 2 < NT) ? (t) + 2 : NT - 1) * BK;                 \
        /* phase 1: Q(0,0) = A0@SX, B0@b0 */                                      \
        STAGE(Bbase, 0, kn1, (OUSo) + 16384);                                     \
        BAR_LG();                                                                 \
        LDA_S(SY, 1, OB);               /* pre-read A1(t) for p2/p3 */            \
        __builtin_amdgcn_s_setprio(1); MFMA_Q(SX, 0, 0, 0); __builtin_amdgcn_s_setprio(0); \
        __builtin_amdgcn_s_barrier();                                             \
        /* phase 2: Q(1,0) = A1@SY, B0@b0 */                                      \
        STAGE(Abase, 1, kn1, (OUSo) + 8192);                                      \
        BAR_LG();                                                                 \
        LDB_S(1, 1, OB);                /* pre-read B1(t) for p3/p4 */            \
        __builtin_amdgcn_s_setprio(1); MFMA_Q(SY, 0, 1, 0); __builtin_amdgcn_s_setprio(0); \
        __builtin_amdgcn_s_barrier();                                             \
        /* phase 3: Q(1,1) = A1@SY, B1@b1 */                                      \
        STAGE(Abase, 0, kn2, (OUS) + 0);                                          \
        BAR_LG();                                                                 \
        __builtin_amdgcn_s_setprio(1); MFMA_Q(SY, 1, 1, 1); __builtin_amdgcn_s_setprio(0); \
        __builtin_amdgcn_s_barrier();                                             \
        /* phase 4: Q(0,1) = A0@SX, B1@b1; pre-read next tile's A0->SY, B0->b0 */ \
        STAGE(Bbase, 1, kn2, (OUS) + 24576);                                      \
        asm volatile("s_waitcnt vmcnt(4)" ::: "memory");                          \
        BAR_LG();                                                                 \
        LDA_S(SY, 0, (OUSo) * 2);                                                 \
        LDB_S(0, 0, (OUSo) * 2);                                                  \
        __builtin_amdgcn_s_setprio(1); MFMA_Q(SX, 1, 0, 1); __builtin_amdgcn_s_setprio(0); \
        __builtin_amdgcn_s_barrier();                                             \
    }

    // prologue: A0(0), B1(0), B0(0), A1(0), A0(1), B1(1); vmcnt(4) leaves
    // A0(1),B1(1) in flight. Then pre-read A0(0)->slot0, B0(0)->b0 (resident).
    STAGE(Abase, 0, 0, 0);
    STAGE(Bbase, 1, 0, 24576);
    STAGE(Bbase, 0, 0, 16384);
    STAGE(Abase, 1, 0, 8192);
    STAGE(Abase, 0, BK, 32768);
    STAGE(Bbase, 1, BK, 32768 + 24576);
    asm volatile("s_waitcnt vmcnt(4)" ::: "memory");
    __builtin_amdgcn_s_barrier();
    LDA_S(0, 0, 0);
    LDB_S(0, 0, 0);

    for (int t = 0; t < NT; t += 2) {
        GROUP(0,     0,     32768, t,     0, 1);
        GROUP(65536, 32768, 0,     t + 1, 1, 0);
    }

    // epilogue: C/D layout col=lane&15, row=(lane>>4)*4+reg
    const int cq = lane >> 4;
    const int cc = lane & 15;
#pragma unroll
    for (int j = 0; j < 4; ++j) {
        const int col = n0 + (4 * j + wn) * 16 + cc;
        const float s = scales[col];
        const float b = bias[col];
#pragma unroll
        for (int i = 0; i < 8; ++i) {
            const int rowb = m0 + (2 * i + wm) * 16 + cq * 4;
#pragma unroll
            for (int r = 0; r < 4; ++r) {
                C[(size_t)(rowb + r) * N + col] = acc[i][j][r] * s + b;
            }
        }
    }
#undef STAGE
#undef LDA_S
#undef LDB_S
#undef BAR_LG
#undef MFMA_Q
#undef GROUP
}

// ---- correctness fallback for unexpected shapes ----
__global__ void naive_kernel(const float* __restrict__ x, const int* __restrict__ wp,
                             const float* __restrict__ sc, const float* __restrict__ bs,
                             float* __restrict__ out, int NR, int OUTF, int INF) {
    int idx = blockIdx.x * 256 + threadIdx.x;
    if (idx >= NR * OUTF) return;
    int n = idx / OUTF, o = idx - n * OUTF;
    const float* xr = x + (size_t)n * INF;
    const int* wr = wp + (size_t)o * (INF / 2);
    float acc = 0.f;
    for (int c = 0; c < INF / 2; ++c) {
        int v = wr[c];
        acc += xr[2 * c] * (float)((v & 0xF) - 8) + xr[2 * c + 1] * (float)(((v >> 4) & 0xF) - 8);
    }
    out[idx] = acc * sc[o] + bs[o];
}

extern "C" void kernel_launch(void* const* d_in, const int* in_sizes, int n_in,
                              void* d_out, int out_size, void* d_ws, size_t ws_size,
                              hipStream_t stream) {
    const float* x      = (const float*)d_in[0];
    const int*   wp     = (const int*)d_in[1];
    const float* scales = (const float*)d_in[2];
    const float* bias   = (const float*)d_in[3];
    float* out = (float*)d_out;

    const int OUTF = in_sizes[2];
    const int INF  = (2 * in_sizes[1]) / OUTF;
    const int NR   = in_sizes[0] / INF;

    unsigned short* xb = (unsigned short*)d_ws;
    unsigned short* wb = xb + (size_t)NR * INF;
    const size_t need = ((size_t)NR * INF + (size_t)OUTF * INF) * sizeof(unsigned short);

    const int GX = OUTF / BN;
    const int GY = NR / BM;

    if (ws_size >= need && INF == 4096 && OUTF == 4096 && (NR % BM) == 0
        && ((GX * GY) % 8) == 0
        && (in_sizes[0] % 8) == 0 && (in_sizes[1] % 4) == 0) {
        prep<<<2048, 256, 0, stream>>>(x, xb, wp, wb, in_sizes[0] / 8, in_sizes[1] / 4);
        gemm_bt<4096, 4096><<<GX * GY, 512, 0, stream>>>(xb, wb, scales, bias, out, GY);
    } else {
        int total = NR * OUTF;
        naive_kernel<<<(total + 255) / 256, 256, 0, stream>>>(x, wp, scales, bias, out, NR, OUTF, INF);
    }
}

// Round 5
// 272.801 us; speedup vs baseline: 1.2558x; 1.2558x over previous
//
#include <hip/hip_runtime.h>
#include <hip/hip_bf16.h>

// QuantizedLinear: out[n][o] = scale[o] * dot(x[n,:], (q[o,:]-8)) + bias[o]
// R10: flatmm-style restructure. R7/R8/R9 (schedule tweaks around the
// verified R6 256x256 8-phase kernel, 128us) all regressed -> the wall is
// structural: B's LDS round-trip + 8-barrier lockstep. Since prep writes the
// weights anyway, it now emits wb in MFMA-FRAGMENT-FLAT order; the GEMM
// loads B fragments global->VGPR (1KB coalesced per wave per frag, L2-
// resident: each XCD's panel pair = 4MB = its L2). LDS holds A only
// (2 x 32KB double buffer), 16 ds_read_b128/wave/K-tile (data minimum),
// ONE barrier + one vmcnt(0) per K-tile (loads issued at tile start have a
// full tile ~2400cyc in flight before the next tile's drain). kk0/kk1 MFMA
// phases keep B regs at 2x16 (budget ~225 VGPR, no spill). Per-acc
// accumulation order unchanged vs R6 (kk0 then kk1 per tile) -> same absmax.
// Kept verified: A chunk-XOR swizzle + pre-swizzled gload_lds source, C/D
// layout + fused epilogue, XCD stripe swizzle, setprio around MFMA.

typedef __attribute__((ext_vector_type(8))) __bf16 bf16x8;
typedef __attribute__((ext_vector_type(4))) float f32x4;

#define GLOBAL_AS __attribute__((address_space(1)))
#define LDS_AS __attribute__((address_space(3)))

#define BM 256
#define BN 256
#define BK 64

__device__ inline unsigned short f32_to_bf16(float f) {
    unsigned int u = __float_as_uint(f);
    unsigned int r = (u + 0x7FFFu + ((u >> 16) & 1u)) >> 16;
    return (unsigned short)r;
}

// ---- preprocessing ----
// x: fp32 -> bf16 linear (unchanged).
// w: packed nibbles -> bf16 in FLAT FRAGMENT layout:
//   ushort index = panel(o>>4)*65536 + t(k>>6)*1024 + kk((k>>5)&1)*512
//                  + aq((k>>3)&3)*128 + am(o&15)*8 + (k&7)
// Lane remap: wave covers am 0..15 x g4 0..3 -> reads 16 full 64B lines,
// writes ONE contiguous 1KB chunk (no partial-line amplification).
__global__ void prep(const float* __restrict__ x, unsigned short* __restrict__ xb,
                     const int* __restrict__ wp, unsigned short* __restrict__ wb,
                     int n8x, int n4w) {
    const int stride = gridDim.x * blockDim.x;
    const int total = n8x + n4w;
    for (int i = blockIdx.x * blockDim.x + threadIdx.x; i < total; i += stride) {
        if (i < n8x) {
            float4 a = ((const float4*)x)[2 * i];
            float4 b = ((const float4*)x)[2 * i + 1];
            union { unsigned short h[8]; uint4 u; } o;
            o.h[0] = f32_to_bf16(a.x); o.h[1] = f32_to_bf16(a.y);
            o.h[2] = f32_to_bf16(a.z); o.h[3] = f32_to_bf16(a.w);
            o.h[4] = f32_to_bf16(b.x); o.h[5] = f32_to_bf16(b.y);
            o.h[6] = f32_to_bf16(b.z); o.h[7] = f32_to_bf16(b.w);
            ((uint4*)xb)[i] = o.u;
        } else {
            const int li = i - n8x;          // n8x = 2^21 -> li wave-coherent
            const int l  = li & 63;
            const int W  = li >> 6;
            const int jb = W >> 7;           // 16-col panel 0..255
            const int gb = W & 127;          // 4-group chunk within panel-row
            const int am = l & 15, g4 = l >> 4;
            const int o_ = jb * 16 + am;     // output col
            const int g  = gb * 4 + g4;      // 8-k group 0..511
            int4 v = ((const int4*)wp)[(size_t)o_ * 512 + g];
            int vals[4] = {v.x, v.y, v.z, v.w};
            union { unsigned short h[8]; uint4 u; } u8;
#pragma unroll
            for (int t2 = 0; t2 < 4; ++t2) {
                u8.h[2 * t2]     = f32_to_bf16((float)((vals[t2] & 0xF) - 8));
                u8.h[2 * t2 + 1] = f32_to_bf16((float)(((vals[t2] >> 4) & 0xF) - 8));
            }
            const int t_ = g >> 3, kk_ = (g >> 2) & 1, aq_ = g & 3;
            ((uint4*)wb)[(jb << 13) | (t_ << 7) | (kk_ << 6) | (aq_ << 4) | am] = u8.u;
        }
    }
}

// ---- main GEMM: C[m][n] = sum_k A[m][k]*B[n][k]; epilogue scale/bias ----
// 256x256 tile, 8 waves (wm=wave>>2, wn=wave&3). LDS = A only:
// buf0 @ ushort 0, buf1 @ 16384; halves A0/A1 at +0/+8192 (bytes 0/16384).
// Per K-tile: [vmcnt(0); barrier; issue B(t,kk1); stage A(t+1);
//   LDA_kk0 (8 ds_read_b128); 32 MFMA; issue B(t+1,kk0); LDA_kk1; 32 MFMA].
template<int K, int N>
__global__ __launch_bounds__(512, 2) void gemm_bt(
    const unsigned short* __restrict__ A,
    const unsigned short* __restrict__ Bf,   // flat fragment layout
    const float* __restrict__ scales,
    const float* __restrict__ bias,
    float* __restrict__ C,
    int GY)
{
    constexpr int NT = K / BK;   // 64 K-tiles
    __shared__ __align__(16) unsigned short lds[32768];  // 64 KiB, A only

    const int tid  = threadIdx.x;
    const int wave = tid >> 6;
    const int lane = tid & 63;
    const int wm = wave >> 2;    // 0..1
    const int wn = wave & 3;     // 0..3

    // XCD swizzle: XCD x = bid&7 owns a 2-column stripe of the 16x16 grid.
    const int bid = blockIdx.x;
    const int chunk = gridDim.x >> 3;
    const int sw = (bid & 7) * chunk + (bid >> 3);
    const int bx = sw / GY;
    const int by = sw - bx * GY;
    const int m0 = by * BM;
    const int n0 = bx * BN;

    // A fragment LDS byte offsets (within a 32KB buffer)
    const int am = lane & 15;
    const int aq = lane >> 4;
    const int cb = ((aq ^ (am & 7)) << 4);   // swizzled chunk byte, kk=0 (^64 kk=1)

    int aoff[8];
#pragma unroll
    for (int i = 0; i < 8; ++i) {
        int r = (2 * i + wm) * 16 + am;               // tile row 0..255
        aoff[i] = ((i < 4) ? 0 : 16384) + (r & 127) * 128 + cb;
    }

    // B flat panel bases (ushort units): wave's col-blocks are 4j+wn
    int bpan[4];
#pragma unroll
    for (int j = 0; j < 4; ++j)
        bpan[j] = ((n0 >> 4) + 4 * j + wn) << 16;
    const int lane8 = lane * 8;

    // A staging: half-tile 128x64 = 1024 16B-chunks; thread covers chunks
    // tid and 512+tid. LDS dest linear; global source pre-swizzled.
    const int sch = tid & 7;
    const int r0 = tid >> 3;
    const int r1 = (512 + tid) >> 3;
    const size_t g0 = (size_t)r0 * K + (size_t)((sch ^ (r0 & 7)) * 8);
    const size_t g1 = (size_t)r1 * K + (size_t)((sch ^ (r1 & 7)) * 8);
    const int d0 = tid * 8;
    const int d1 = (512 + tid) * 8;

    const unsigned short* Abase = A + (size_t)m0 * K;

    f32x4 acc[8][4];
#pragma unroll
    for (int i = 0; i < 8; ++i)
#pragma unroll
        for (int j = 0; j < 4; ++j)
            acc[i][j] = (f32x4){0.f, 0.f, 0.f, 0.f};

    const char* ldsB = (const char*)lds;
    bf16x8 af8[8];        // A frags, one kk at a time (32 VGPR)
    bf16x8 bX[4], bY[4];  // B frags kk0 / kk1 (16+16 VGPR)

#define STAGE(half, kcol, uoff)                                                   \
    do {                                                                          \
        const unsigned short* _g = Abase + (size_t)((half) * 128) * K + (kcol);   \
        __builtin_amdgcn_global_load_lds((const GLOBAL_AS void*)(_g + g0),        \
            (LDS_AS void*)(lds + (uoff) + d0), 16, 0, 0);                         \
        __builtin_amdgcn_global_load_lds((const GLOBAL_AS void*)(_g + g1),        \
            (LDS_AS void*)(lds + (uoff) + d1), 16, 0, 0);                         \
    } while (0)

#define LDA_KK(kkv, OBb)                                                          \
    _Pragma("unroll") for (int i2 = 0; i2 < 8; ++i2) {                            \
        af8[i2] = *(const bf16x8*)(ldsB + (OBb) + (aoff[i2] ^ ((kkv) * 64)));     \
    }

#define LDBG(dst, TT2, kkv)                                                       \
    _Pragma("unroll") for (int j2 = 0; j2 < 4; ++j2) {                            \
        dst[j2] = *(const bf16x8*)(Bf + (size_t)bpan[j2] + (TT2) * 1024           \
                                   + (kkv) * 512 + lane8);                        \
    }

#define MFMA_PH(bset)                                                             \
    _Pragma("unroll") for (int i2 = 0; i2 < 8; ++i2)                              \
    _Pragma("unroll") for (int j2 = 0; j2 < 4; ++j2)                              \
        acc[i2][j2] = __builtin_amdgcn_mfma_f32_16x16x32_bf16(                    \
            af8[i2], bset[j2], acc[i2][j2], 0, 0, 0);

// One K-tile. OBb = byte offset of current A buffer; OUSo = ushort offset of
// the OTHER buffer (staging target). All in-flight VMEM (B(t,kk0)+B(t,kk1
// from prev tile? no: B(t,kk0) from prev ph2, A(t) staging from prev ph1)
// drains at the tile-start vmcnt(0) with ~a full tile in flight.
#define TILE(TT, OBb, OUSo)                                                       \
    {                                                                             \
        const int tn = (((TT) + 1 < NT) ? (TT) + 1 : NT - 1);                     \
        asm volatile("s_waitcnt vmcnt(0)" ::: "memory");                          \
        __builtin_amdgcn_s_barrier();                                             \
        LDBG(bY, (TT), 1);                   /* B(t,kk1), used in ph2 */          \
        STAGE(0, tn * BK, (OUSo));           /* A(t+1) -> other buf */            \
        STAGE(1, tn * BK, (OUSo) + 8192);                                         \
        LDA_KK(0, OBb);                                                           \
        __builtin_amdgcn_s_setprio(1); MFMA_PH(bX); __builtin_amdgcn_s_setprio(0);\
        LDBG(bX, tn, 0);                     /* B(t+1,kk0) for next tile */       \
        LDA_KK(1, OBb);                                                           \
        __builtin_amdgcn_s_setprio(1); MFMA_PH(bY); __builtin_amdgcn_s_setprio(0);\
    }

    // prologue: A(0) -> buf0, B(0,kk0) -> bX
    STAGE(0, 0, 0);
    STAGE(1, 0, 8192);
    LDBG(bX, 0, 0);

    for (int t = 0; t < NT; t += 2) {
        TILE(t, 0, 16384);
        TILE(t + 1, 32768, 0);
    }
    asm volatile("s_waitcnt vmcnt(0)" ::: "memory");  // drain tail loads

    // epilogue: C/D layout col=lane&15, row=(lane>>4)*4+reg
    const int cq = lane >> 4;
    const int cc = lane & 15;
#pragma unroll
    for (int j = 0; j < 4; ++j) {
        const int col = n0 + (4 * j + wn) * 16 + cc;
        const float s = scales[col];
        const float b = bias[col];
#pragma unroll
        for (int i = 0; i < 8; ++i) {
            const int rowb = m0 + (2 * i + wm) * 16 + cq * 4;
#pragma unroll
            for (int r = 0; r < 4; ++r) {
                C[(size_t)(rowb + r) * N + col] = acc[i][j][r] * s + b;
            }
        }
    }
#undef STAGE
#undef LDA_KK
#undef LDBG
#undef MFMA_PH
#undef TILE
}

// ---- correctness fallback for unexpected shapes ----
__global__ void naive_kernel(const float* __restrict__ x, const int* __restrict__ wp,
                             const float* __restrict__ sc, const float* __restrict__ bs,
                             float* __restrict__ out, int NR, int OUTF, int INF) {
    int idx = blockIdx.x * 256 + threadIdx.x;
    if (idx >= NR * OUTF) return;
    int n = idx / OUTF, o = idx - n * OUTF;
    const float* xr = x + (size_t)n * INF;
    const int* wr = wp + (size_t)o * (INF / 2);
    float acc = 0.f;
    for (int c = 0; c < INF / 2; ++c) {
        int v = wr[c];
        acc += xr[2 * c] * (float)((v & 0xF) - 8) + xr[2 * c + 1] * (float)(((v >> 4) & 0xF) - 8);
    }
    out[idx] = acc * sc[o] + bs[o];
}

extern "C" void kernel_launch(void* const* d_in, const int* in_sizes, int n_in,
                              void* d_out, int out_size, void* d_ws, size_t ws_size,
                              hipStream_t stream) {
    const float* x      = (const float*)d_in[0];
    const int*   wp     = (const int*)d_in[1];
    const float* scales = (const float*)d_in[2];
    const float* bias   = (const float*)d_in[3];
    float* out = (float*)d_out;

    const int OUTF = in_sizes[2];
    const int INF  = (2 * in_sizes[1]) / OUTF;
    const int NR   = in_sizes[0] / INF;

    unsigned short* xb = (unsigned short*)d_ws;
    unsigned short* wb = xb + (size_t)NR * INF;
    const size_t need = ((size_t)NR * INF + (size_t)OUTF * INF) * sizeof(unsigned short);

    const int GX = OUTF / BN;
    const int GY = NR / BM;

    if (ws_size >= need && INF == 4096 && OUTF == 4096 && NR == 4096
        && ((GX * GY) % 8) == 0
        && (in_sizes[0] % 8) == 0 && (in_sizes[1] % 4) == 0) {
        prep<<<2048, 256, 0, stream>>>(x, xb, wp, wb, in_sizes[0] / 8, in_sizes[1] / 4);
        gemm_bt<4096, 4096><<<GX * GY, 512, 0, stream>>>(xb, wb, scales, bias, out, GY);
    } else {
        int total = NR * OUTF;
        naive_kernel<<<(total + 255) / 256, 256, 0, stream>>>(x, wp, scales, bias, out, NR, OUTF, INF);
    }
}

// Round 6
// 270.236 us; speedup vs baseline: 1.2677x; 1.0095x over previous
//
#include <hip/hip_runtime.h>
#include <hip/hip_bf16.h>

// QuantizedLinear: out[n][o] = scale[o] * dot(x[n,:], (q[o,:]-8)) + bias[o]
// R11 = R10 (flatmm structure: B global->VGPR in fragment-flat layout, LDS =
// A only 2x32KB, one barrier per K-tile; 131us/45% MfmaUtil) with the
// A-fragment WAR serialization removed. R6..R10 all alternated
// [ds_read burst][MFMA cluster] within each wave because the af registers
// were single-buffered -> CU wall = LDS-time + MFMA-time. Now af is split
// lo(rows0-3)/hi(rows4-7) and the tile is software-pipelined at
// half-granularity with ZERO extra registers (R9's idea without R9's spill):
//   read lo(kk0); [read hi(kk0) || MFMA lo*bX]; [read lo(kk1) || MFMA hi*bX];
//   [read hi(kk1) + issue B(t+1,kk0) || MFMA lo*bY]; [MFMA hi*bY]
// Each 4-read burst completes under an independent 16-MFMA cluster; WAR
// anti-deps (reload after consumption) are enforced by program order; all
// lgkm waits are compiler SSA (fine-grained). Tile-start drain is now a
// COUNTED vmcnt(4): A(t) staging loads are provably older than the newest 4
// B-register loads, and per-wave drain + barrier still gives cross-wave LDS
// visibility. B prefetch slack >= ~1400cyc (covers HBM miss). Accumulation
// order per acc element unchanged (kk0 then kk1 per tile) -> same absmax.
// Kept: fragment-flat prep for B, A chunk-XOR swizzle + pre-swizzled
// gload_lds source, C/D layout + fused epilogue, XCD stripe swizzle,
// setprio around MFMA clusters.

typedef __attribute__((ext_vector_type(8))) __bf16 bf16x8;
typedef __attribute__((ext_vector_type(4))) float f32x4;

#define GLOBAL_AS __attribute__((address_space(1)))
#define LDS_AS __attribute__((address_space(3)))

#define BM 256
#define BN 256
#define BK 64

__device__ inline unsigned short f32_to_bf16(float f) {
    unsigned int u = __float_as_uint(f);
    unsigned int r = (u + 0x7FFFu + ((u >> 16) & 1u)) >> 16;
    return (unsigned short)r;
}

// ---- preprocessing ----
// x: fp32 -> bf16 linear (unchanged).
// w: packed nibbles -> bf16 in FLAT FRAGMENT layout:
//   ushort index = panel(o>>4)*65536 + t(k>>6)*1024 + kk((k>>5)&1)*512
//                  + aq((k>>3)&3)*128 + am(o&15)*8 + (k&7)
__global__ void prep(const float* __restrict__ x, unsigned short* __restrict__ xb,
                     const int* __restrict__ wp, unsigned short* __restrict__ wb,
                     int n8x, int n4w) {
    const int stride = gridDim.x * blockDim.x;
    const int total = n8x + n4w;
    for (int i = blockIdx.x * blockDim.x + threadIdx.x; i < total; i += stride) {
        if (i < n8x) {
            float4 a = ((const float4*)x)[2 * i];
            float4 b = ((const float4*)x)[2 * i + 1];
            union { unsigned short h[8]; uint4 u; } o;
            o.h[0] = f32_to_bf16(a.x); o.h[1] = f32_to_bf16(a.y);
            o.h[2] = f32_to_bf16(a.z); o.h[3] = f32_to_bf16(a.w);
            o.h[4] = f32_to_bf16(b.x); o.h[5] = f32_to_bf16(b.y);
            o.h[6] = f32_to_bf16(b.z); o.h[7] = f32_to_bf16(b.w);
            ((uint4*)xb)[i] = o.u;
        } else {
            const int li = i - n8x;          // n8x = 2^21 -> li wave-coherent
            const int l  = li & 63;
            const int W  = li >> 6;
            const int jb = W >> 7;           // 16-col panel 0..255
            const int gb = W & 127;          // 4-group chunk within panel-row
            const int am = l & 15, g4 = l >> 4;
            const int o_ = jb * 16 + am;     // output col
            const int g  = gb * 4 + g4;      // 8-k group 0..511
            int4 v = ((const int4*)wp)[(size_t)o_ * 512 + g];
            int vals[4] = {v.x, v.y, v.z, v.w};
            union { unsigned short h[8]; uint4 u; } u8;
#pragma unroll
            for (int t2 = 0; t2 < 4; ++t2) {
                u8.h[2 * t2]     = f32_to_bf16((float)((vals[t2] & 0xF) - 8));
                u8.h[2 * t2 + 1] = f32_to_bf16((float)(((vals[t2] >> 4) & 0xF) - 8));
            }
            const int t_ = g >> 3, kk_ = (g >> 2) & 1, aq_ = g & 3;
            ((uint4*)wb)[(jb << 13) | (t_ << 7) | (kk_ << 6) | (aq_ << 4) | am] = u8.u;
        }
    }
}

// ---- main GEMM: C[m][n] = sum_k A[m][k]*B[n][k]; epilogue scale/bias ----
// 256x256 tile, 8 waves (wm=wave>>2, wn=wave&3). LDS = A only:
// buf0 @ ushort 0, buf1 @ 16384; halves A0/A1 at +0/+8192.
template<int K, int N>
__global__ __launch_bounds__(512, 2) void gemm_bt(
    const unsigned short* __restrict__ A,
    const unsigned short* __restrict__ Bf,   // flat fragment layout
    const float* __restrict__ scales,
    const float* __restrict__ bias,
    float* __restrict__ C,
    int GY)
{
    constexpr int NT = K / BK;   // 64 K-tiles
    __shared__ __align__(16) unsigned short lds[32768];  // 64 KiB, A only

    const int tid  = threadIdx.x;
    const int wave = tid >> 6;
    const int lane = tid & 63;
    const int wm = wave >> 2;    // 0..1
    const int wn = wave & 3;     // 0..3

    // XCD swizzle: XCD x = bid&7 owns a 2-column stripe of the 16x16 grid.
    const int bid = blockIdx.x;
    const int chunk = gridDim.x >> 3;
    const int sw = (bid & 7) * chunk + (bid >> 3);
    const int bx = sw / GY;
    const int by = sw - bx * GY;
    const int m0 = by * BM;
    const int n0 = bx * BN;

    // A fragment LDS byte offsets (within a 32KB buffer)
    const int am = lane & 15;
    const int aq = lane >> 4;
    const int cb = ((aq ^ (am & 7)) << 4);   // swizzled chunk byte, kk=0 (^64 kk=1)

    int aoff[8];
#pragma unroll
    for (int i = 0; i < 8; ++i) {
        int r = (2 * i + wm) * 16 + am;               // tile row 0..255
        aoff[i] = ((i < 4) ? 0 : 16384) + (r & 127) * 128 + cb;
    }

    // B flat panel bases (ushort units): wave's col-blocks are 4j+wn
    int bpan[4];
#pragma unroll
    for (int j = 0; j < 4; ++j)
        bpan[j] = ((n0 >> 4) + 4 * j + wn) << 16;
    const int lane8 = lane * 8;

    // A staging: half-tile 128x64 = 1024 16B-chunks; thread covers chunks
    // tid and 512+tid. LDS dest linear; global source pre-swizzled.
    const int sch = tid & 7;
    const int r0 = tid >> 3;
    const int r1 = (512 + tid) >> 3;
    const size_t g0 = (size_t)r0 * K + (size_t)((sch ^ (r0 & 7)) * 8);
    const size_t g1 = (size_t)r1 * K + (size_t)((sch ^ (r1 & 7)) * 8);
    const int d0 = tid * 8;
    const int d1 = (512 + tid) * 8;

    const unsigned short* Abase = A + (size_t)m0 * K;

    f32x4 acc[8][4];
#pragma unroll
    for (int i = 0; i < 8; ++i)
#pragma unroll
        for (int j = 0; j < 4; ++j)
            acc[i][j] = (f32x4){0.f, 0.f, 0.f, 0.f};

    const char* ldsB = (const char*)lds;
    bf16x8 af8[8];        // rows 0-3 = lo, 4-7 = hi; reloaded per kk (32 VGPR)
    bf16x8 bX[4], bY[4];  // B frags kk0 / kk1 (16+16 VGPR)

#define STAGE(half, kcol, uoff)                                                   \
    do {                                                                          \
        const unsigned short* _g = Abase + (size_t)((half) * 128) * K + (kcol);   \
        __builtin_amdgcn_global_load_lds((const GLOBAL_AS void*)(_g + g0),        \
            (LDS_AS void*)(lds + (uoff) + d0), 16, 0, 0);                         \
        __builtin_amdgcn_global_load_lds((const GLOBAL_AS void*)(_g + g1),        \
            (LDS_AS void*)(lds + (uoff) + d1), 16, 0, 0);                         \
    } while (0)

// read A half (0=lo rows0-3, 1=hi rows4-7) for kk into af8[half*4..+3]
#define LDA_H(half, kkv, OBb)                                                     \
    _Pragma("unroll") for (int i2 = 0; i2 < 4; ++i2) {                            \
        af8[(half) * 4 + i2] =                                                    \
            *(const bf16x8*)(ldsB + (OBb) + (aoff[(half) * 4 + i2] ^ ((kkv) * 64))); \
    }

#define LDBG(dst, TT2, kkv)                                                       \
    _Pragma("unroll") for (int j2 = 0; j2 < 4; ++j2) {                            \
        dst[j2] = *(const bf16x8*)(Bf + (size_t)bpan[j2] + (TT2) * 1024           \
                                   + (kkv) * 512 + lane8);                        \
    }

// 16 MFMA: rows of one half x all 4 col-frags
#define MFMA_H(half, bset)                                                        \
    _Pragma("unroll") for (int i2 = 0; i2 < 4; ++i2)                              \
    _Pragma("unroll") for (int j2 = 0; j2 < 4; ++j2)                              \
        acc[(half) * 4 + i2][j2] = __builtin_amdgcn_mfma_f32_16x16x32_bf16(       \
            af8[(half) * 4 + i2], bset[j2], acc[(half) * 4 + i2][j2], 0, 0, 0);

// One K-tile. OBb = byte offset of current A buffer; OUSo = ushort offset of
// the other buffer (staging target). Counted vmcnt(4): at tile start the
// outstanding VMEM ops are (oldest->newest) [A(t) staging x4][bX(t) x4];
// waiting to <=4 drains A(t) (LDS-visible after the barrier across all
// waves) while bX(t) stays in flight (register loads, compiler SSA waits).
#define TILE(TT, OBb, OUSo)                                                       \
    {                                                                             \
        const int tn = (((TT) + 1 < NT) ? (TT) + 1 : NT - 1);                     \
        asm volatile("s_waitcnt vmcnt(4)" ::: "memory");                          \
        __builtin_amdgcn_s_barrier();                                             \
        LDBG(bY, (TT), 1);                   /* B(t,kk1), used 2 clusters later */\
        STAGE(0, tn * BK, (OUSo));           /* A(t+1) -> other buf */            \
        STAGE(1, tn * BK, (OUSo) + 8192);                                         \
        LDA_H(0, 0, OBb);                    /* lo kk0 */                         \
        LDA_H(1, 0, OBb);                    /* hi kk0 (completes under MFMA) */  \
        __builtin_amdgcn_s_setprio(1); MFMA_H(0, bX); __builtin_amdgcn_s_setprio(0); \
        LDA_H(0, 1, OBb);                    /* lo kk1 (WAR: after lo consumed) */\
        __builtin_amdgcn_s_setprio(1); MFMA_H(1, bX); __builtin_amdgcn_s_setprio(0); \
        LDBG(bX, tn, 0);                     /* B(t+1,kk0): ~2 clusters slack */  \
        LDA_H(1, 1, OBb);                    /* hi kk1 */                         \
        __builtin_amdgcn_s_setprio(1); MFMA_H(0, bY); __builtin_amdgcn_s_setprio(0); \
        __builtin_amdgcn_s_setprio(1); MFMA_H(1, bY); __builtin_amdgcn_s_setprio(0); \
    }

    // prologue: A(0) -> buf0, B(0,kk0) -> bX
    STAGE(0, 0, 0);
    STAGE(1, 0, 8192);
    LDBG(bX, 0, 0);

    for (int t = 0; t < NT; t += 2) {
        TILE(t, 0, 16384);
        TILE(t + 1, 32768, 0);
    }
    asm volatile("s_waitcnt vmcnt(0)" ::: "memory");  // drain tail loads

    // epilogue: C/D layout col=lane&15, row=(lane>>4)*4+reg
    const int cq = lane >> 4;
    const int cc = lane & 15;
#pragma unroll
    for (int j = 0; j < 4; ++j) {
        const int col = n0 + (4 * j + wn) * 16 + cc;
        const float s = scales[col];
        const float b = bias[col];
#pragma unroll
        for (int i = 0; i < 8; ++i) {
            const int rowb = m0 + (2 * i + wm) * 16 + cq * 4;
#pragma unroll
            for (int r = 0; r < 4; ++r) {
                C[(size_t)(rowb + r) * N + col] = acc[i][j][r] * s + b;
            }
        }
    }
#undef STAGE
#undef LDA_H
#undef LDBG
#undef MFMA_H
#undef TILE
}

// ---- correctness fallback for unexpected shapes ----
__global__ void naive_kernel(const float* __restrict__ x, const int* __restrict__ wp,
                             const float* __restrict__ sc, const float* __restrict__ bs,
                             float* __restrict__ out, int NR, int OUTF, int INF) {
    int idx = blockIdx.x * 256 + threadIdx.x;
    if (idx >= NR * OUTF) return;
    int n = idx / OUTF, o = idx - n * OUTF;
    const float* xr = x + (size_t)n * INF;
    const int* wr = wp + (size_t)o * (INF / 2);
    float acc = 0.f;
    for (int c = 0; c < INF / 2; ++c) {
        int v = wr[c];
        acc += xr[2 * c] * (float)((v & 0xF) - 8) + xr[2 * c + 1] * (float)(((v >> 4) & 0xF) - 8);
    }
    out[idx] = acc * sc[o] + bs[o];
}

extern "C" void kernel_launch(void* const* d_in, const int* in_sizes, int n_in,
                              void* d_out, int out_size, void* d_ws, size_t ws_size,
                              hipStream_t stream) {
    const float* x      = (const float*)d_in[0];
    const int*   wp     = (const int*)d_in[1];
    const float* scales = (const float*)d_in[2];
    const float* bias   = (const float*)d_in[3];
    float* out = (float*)d_out;

    const int OUTF = in_sizes[2];
    const int INF  = (2 * in_sizes[1]) / OUTF;
    const int NR   = in_sizes[0] / INF;

    unsigned short* xb = (unsigned short*)d_ws;
    unsigned short* wb = xb + (size_t)NR * INF;
    const size_t need = ((size_t)NR * INF + (size_t)OUTF * INF) * sizeof(unsigned short);

    const int GX = OUTF / BN;
    const int GY = NR / BM;

    if (ws_size >= need && INF == 4096 && OUTF == 4096 && NR == 4096
        && ((GX * GY) % 8) == 0
        && (in_sizes[0] % 8) == 0 && (in_sizes[1] % 4) == 0) {
        prep<<<2048, 256, 0, stream>>>(x, xb, wp, wb, in_sizes[0] / 8, in_sizes[1] / 4);
        gemm_bt<4096, 4096><<<GX * GY, 512, 0, stream>>>(xb, wb, scales, bias, out, GY);
    } else {
        int total = NR * OUTF;
        naive_kernel<<<(total + 255) / 256, 256, 0, stream>>>(x, wp, scales, bias, out, NR, OUTF, INF);
    }
}